// Round 12
// baseline (193.438 us; speedup 1.0000x reference)
//
#include <hip/hip_runtime.h>
#include <hip/hip_bf16.h>
#include <math.h>

#define MAXDEG 64

__device__ __forceinline__ float lrelu(float v) { return v > 0.0f ? v : 0.2f * v; }

// ---- Zero the counts buffer (replaces pathologically-slow rocclr fill kernel)
__global__ void zero_kernel(int4* __restrict__ p, int n4) {
  int i = blockIdx.x * 256 + threadIdx.x;
  if (i < n4) p[i] = make_int4(0, 0, 0, 0);
}

// ---- Kernel A: fold attention vectors into W: wsrc[k,h] = sum_c W[k,h*64+c]*att_src[h,c]
__global__ void patt_kernel(const float* __restrict__ W, const float* __restrict__ att_src,
                            const float* __restrict__ att_dst, float* __restrict__ wsrc,
                            float* __restrict__ wdst) {
  int t = threadIdx.x;  // 256 threads: h = t>>6, k = t&63
  int h = t >> 6, k = t & 63;
  const float* wrow = W + (size_t)k * 256 + h * 64;
  const float* as = att_src + h * 64;
  const float* ad = att_dst + h * 64;
  float ss = 0.f, sd = 0.f;
#pragma unroll
  for (int c = 0; c < 64; ++c) {
    float w = wrow[c];
    ss = fmaf(w, as[c], ss);
    sd = fmaf(w, ad[c], sd);
  }
  wsrc[k * 4 + h] = ss;
  wdst[k * 4 + h] = sd;
}

// ---- Kernel B: per-node attention scalars + bf16 copy of x (side product).
__global__ void nattn_kernel(const float* __restrict__ x, const float4* __restrict__ wsrc4,
                             const float4* __restrict__ wdst4, float4* __restrict__ asrc4,
                             float4* __restrict__ adst4, __hip_bfloat16* __restrict__ xh,
                             int N) {
  int lane = threadIdx.x & 63;
  int n = blockIdx.x * 4 + (threadIdx.x >> 6);
  if (n >= N) return;
  float xv = x[(size_t)n * 64 + lane];
  xh[(size_t)n * 64 + lane] = __float2bfloat16(xv);
  float4 ws = wsrc4[lane], wd = wdst4[lane];
  float s0 = xv * ws.x, s1 = xv * ws.y, s2 = xv * ws.z, s3 = xv * ws.w;
  float d0 = xv * wd.x, d1 = xv * wd.y, d2 = xv * wd.z, d3 = xv * wd.w;
#pragma unroll
  for (int m = 1; m < 64; m <<= 1) {
    s0 += __shfl_xor(s0, m, 64); s1 += __shfl_xor(s1, m, 64);
    s2 += __shfl_xor(s2, m, 64); s3 += __shfl_xor(s3, m, 64);
    d0 += __shfl_xor(d0, m, 64); d1 += __shfl_xor(d1, m, 64);
    d2 += __shfl_xor(d2, m, 64); d3 += __shfl_xor(d3, m, 64);
  }
  if (lane == 0) {
    asrc4[n] = make_float4(s0, s1, s2, s3);
    adst4[n] = make_float4(d0, d1, d2, d3);
  }
}

// ---- Scalar hist/scatter [round-2 proven, fallback when E%4 != 0]
__global__ void hist_kernel(const int* __restrict__ ei, int* __restrict__ counts,
                            int E, int N) {
  int e = blockIdx.x * 256 + threadIdx.x;
  int ET = E + N;
  if (e >= ET) return;
  int dst = (e < E) ? ei[(size_t)E + e] : (e - E);
  atomicAdd(&counts[dst], 1);
}

__global__ void scatter_kernel(const int* __restrict__ ei, int* __restrict__ cursor,
                               int* __restrict__ src_sorted, int E, int N) {
  int e = blockIdx.x * 256 + threadIdx.x;
  int ET = E + N;
  if (e >= ET) return;
  int src, dst;
  if (e < E) {
    src = ei[e];
    dst = ei[(size_t)E + e];
  } else {
    src = dst = e - E;
  }
  int pos = atomicAdd(&cursor[dst], 1);
  src_sorted[pos] = src;
}

// ---- int4 hist (E%4==0 path) [proven r8]
__global__ void hist4_kernel(const int* __restrict__ ei, int* __restrict__ counts,
                             int E, int N) {
  int i = blockIdx.x * 256 + threadIdx.x;
  int E4 = E >> 2;
  if (i < E4) {
    int4 d = ((const int4*)(ei + E))[i];
    atomicAdd(&counts[d.x], 1);
    atomicAdd(&counts[d.y], 1);
    atomicAdd(&counts[d.z], 1);
    atomicAdd(&counts[d.w], 1);
  } else if (i < E4 + N) {
    atomicAdd(&counts[i - E4], 1);
  }
}

// ---- XCD-sliced scatter [proven r9]
__global__ void scatter8_kernel(const int* __restrict__ ei, int* __restrict__ cursor,
                                int* __restrict__ srt, int E, int N) {
  int slice = blockIdx.x & 7;
  int bid = blockIdx.x >> 3;
  int nb = gridDim.x >> 3;
  int chunk = (N + 7) >> 3;
  int lo = slice * chunk;
  int hi = lo + chunk; if (hi > N) hi = N;
  int E4 = E >> 2;
  const int4* s4p = (const int4*)ei;
  const int4* d4p = (const int4*)(ei + E);
  int stride = nb * 256;
  for (int i = bid * 256 + threadIdx.x; i < E4; i += stride) {
    int4 d4 = d4p[i];
    bool bx = (d4.x >= lo && d4.x < hi), by = (d4.y >= lo && d4.y < hi);
    bool bz = (d4.z >= lo && d4.z < hi), bw = (d4.w >= lo && d4.w < hi);
    if (!(bx || by || bz || bw)) continue;
    int4 s4 = s4p[i];
    if (bx) { int p = atomicAdd(&cursor[d4.x], 1); srt[p] = s4.x; }
    if (by) { int p = atomicAdd(&cursor[d4.y], 1); srt[p] = s4.y; }
    if (bz) { int p = atomicAdd(&cursor[d4.z], 1); srt[p] = s4.z; }
    if (bw) { int p = atomicAdd(&cursor[d4.w], 1); srt[p] = s4.w; }
  }
  for (int n = lo + bid * 256 + threadIdx.x; n < hi; n += stride) {
    int p = atomicAdd(&cursor[n], 1);
    srt[p] = n;
  }
}

// ---- Hierarchical scan [proven r5]
__global__ void scanA_kernel(const int* __restrict__ cnt, int* __restrict__ tsum, int N) {
  int b = blockIdx.x, t = threadIdx.x;
  int idx = b * 256 + t;
  int v = (idx < N) ? cnt[idx] : 0;
#pragma unroll
  for (int m = 1; m < 64; m <<= 1) v += __shfl_xor(v, m, 64);
  __shared__ int ws[4];
  if ((t & 63) == 0) ws[t >> 6] = v;
  __syncthreads();
  if (t == 0) tsum[b] = ws[0] + ws[1] + ws[2] + ws[3];
}

__global__ void scanB_kernel(int* __restrict__ tsum, int ntiles) {
  __shared__ int part[256];
  int t = threadIdx.x;
  int carry = 0;
  for (int b0 = 0; b0 < ntiles; b0 += 256) {
    int idx = b0 + t;
    int v = (idx < ntiles) ? tsum[idx] : 0;
    part[t] = v;
    __syncthreads();
    for (int d = 1; d < 256; d <<= 1) {
      int u = (t >= d) ? part[t - d] : 0;
      __syncthreads();
      part[t] += u;
      __syncthreads();
    }
    if (idx < ntiles) tsum[idx] = part[t] - v + carry;  // exclusive + carry
    carry += part[255];
    __syncthreads();
  }
}

__global__ void scanC_kernel(const int* __restrict__ cnt, const int* __restrict__ tsum,
                             int* __restrict__ row, int* __restrict__ cur, int N) {
  __shared__ int part[256];
  int b = blockIdx.x, t = threadIdx.x;
  int idx = b * 256 + t;
  int c = (idx < N) ? cnt[idx] : 0;
  part[t] = c;
  __syncthreads();
  for (int d = 1; d < 256; d <<= 1) {
    int u = (t >= d) ? part[t - d] : 0;
    __syncthreads();
    part[t] += u;
    __syncthreads();
  }
  int exc = part[t] - c + tsum[b];
  if (idx < N) {
    row[idx] = exc;
    cur[idx] = exc;
    if (idx == N - 1) row[N] = exc + c;
  }
}

// ---- Aggregation: one wave per node, zero barriers; x gathered as bf16 [proven r10]
__global__ __launch_bounds__(256) void agg_kernel(
    const int* __restrict__ srt, const int* __restrict__ row,
    const float4* __restrict__ asrc4, const float4* __restrict__ adst4,
    const __hip_bfloat16* __restrict__ xh, float* __restrict__ agg, int N) {
  __shared__ float4 alL[4][MAXDEG];  // 4096B
  __shared__ int slL[4][MAXDEG];     // 1024B
  int t = threadIdx.x, w = t >> 6, lane = t & 63;
  int n = blockIdx.x * 4 + w;
  if (n >= N) return;
  int start = row[n], end = row[n + 1];
  int deg = end - start;
  float4 ad = adst4[n];
  float t0 = 0.f, t1 = 0.f, t2 = 0.f, t3 = 0.f;
  if (deg <= MAXDEG) {
    for (int b = 0; b < deg; b += 64) {
      if (b + lane < deg) {
        int sl = srt[start + b + lane];
        float4 as = asrc4[sl];
        float4 e;
        e.x = __expf(lrelu(as.x + ad.x));
        e.y = __expf(lrelu(as.y + ad.y));
        e.z = __expf(lrelu(as.z + ad.z));
        e.w = __expf(lrelu(as.w + ad.w));
        alL[w][b + lane] = e;
        slL[w][b + lane] = sl;
        t0 += e.x; t1 += e.y; t2 += e.z; t3 += e.w;
      }
    }
  } else {
    for (int b = start; b < end; b += 64) {
      int idx = b + lane;
      if (idx < end) {
        int sl = srt[idx];
        float4 as = asrc4[sl];
        t0 += __expf(lrelu(as.x + ad.x));
        t1 += __expf(lrelu(as.y + ad.y));
        t2 += __expf(lrelu(as.z + ad.z));
        t3 += __expf(lrelu(as.w + ad.w));
      }
    }
  }
#pragma unroll
  for (int m = 1; m < 64; m <<= 1) {
    t0 += __shfl_xor(t0, m, 64);
    t1 += __shfl_xor(t1, m, 64);
    t2 += __shfl_xor(t2, m, 64);
    t3 += __shfl_xor(t3, m, 64);
  }
  float r0 = 0.25f / (t0 + 1e-16f), r1 = 0.25f / (t1 + 1e-16f);
  float r2 = 0.25f / (t2 + 1e-16f), r3 = 0.25f / (t3 + 1e-16f);
  float a0 = 0.f, a1 = 0.f, a2 = 0.f, a3 = 0.f;
  if (deg <= MAXDEG) {
    int j = 0;
    for (; j + 4 <= deg; j += 4) {
      float4 e0 = alL[w][j], e1 = alL[w][j + 1], e2 = alL[w][j + 2], e3 = alL[w][j + 3];
      int q0 = slL[w][j], q1 = slL[w][j + 1], q2 = slL[w][j + 2], q3 = slL[w][j + 3];
      float v0 = __bfloat162float(xh[(size_t)q0 * 64 + lane]);
      float v1 = __bfloat162float(xh[(size_t)q1 * 64 + lane]);
      float v2 = __bfloat162float(xh[(size_t)q2 * 64 + lane]);
      float v3 = __bfloat162float(xh[(size_t)q3 * 64 + lane]);
      a0 = fmaf(e0.x, v0, a0); a1 = fmaf(e0.y, v0, a1);
      a2 = fmaf(e0.z, v0, a2); a3 = fmaf(e0.w, v0, a3);
      a0 = fmaf(e1.x, v1, a0); a1 = fmaf(e1.y, v1, a1);
      a2 = fmaf(e1.z, v1, a2); a3 = fmaf(e1.w, v1, a3);
      a0 = fmaf(e2.x, v2, a0); a1 = fmaf(e2.y, v2, a1);
      a2 = fmaf(e2.z, v2, a2); a3 = fmaf(e2.w, v2, a3);
      a0 = fmaf(e3.x, v3, a0); a1 = fmaf(e3.y, v3, a1);
      a2 = fmaf(e3.z, v3, a2); a3 = fmaf(e3.w, v3, a3);
    }
    for (; j < deg; ++j) {
      float4 e0 = alL[w][j];
      int q0 = slL[w][j];
      float v0 = __bfloat162float(xh[(size_t)q0 * 64 + lane]);
      a0 = fmaf(e0.x, v0, a0); a1 = fmaf(e0.y, v0, a1);
      a2 = fmaf(e0.z, v0, a2); a3 = fmaf(e0.w, v0, a3);
    }
  } else {
    for (int b = start; b < end; b += 64) {
      int cnt = end - b;
      if (cnt > 64) cnt = 64;
      int idx = b + lane;
      int sl = 0;
      float e0 = 0.f, e1 = 0.f, e2 = 0.f, e3 = 0.f;
      if (idx < end) {
        sl = srt[idx];
        float4 as = asrc4[sl];
        e0 = __expf(lrelu(as.x + ad.x));
        e1 = __expf(lrelu(as.y + ad.y));
        e2 = __expf(lrelu(as.z + ad.z));
        e3 = __expf(lrelu(as.w + ad.w));
      }
      for (int j = 0; j < cnt; ++j) {
        int sj = __shfl(sl, j, 64);
        float b0 = __shfl(e0, j, 64), b1 = __shfl(e1, j, 64);
        float b2 = __shfl(e2, j, 64), b3 = __shfl(e3, j, 64);
        float v = __bfloat162float(xh[(size_t)sj * 64 + lane]);
        a0 = fmaf(b0, v, a0); a1 = fmaf(b1, v, a1);
        a2 = fmaf(b2, v, a2); a3 = fmaf(b3, v, a3);
      }
    }
  }
  float* ao = agg + (size_t)n * 256;
  ao[lane] = a0 * r0;
  ao[64 + lane] = a1 * r1;
  ao[128 + lane] = a2 * r2;
  ao[192 + lane] = a3 * r3;
}

// ---- Projection [proven r8]
__global__ __launch_bounds__(256) void proj_kernel(
    const float* __restrict__ agg, const float* __restrict__ W,
    const float* __restrict__ bias, float* __restrict__ out, int N) {
  __shared__ float aggL[4][256];   // 4KB
  __shared__ float pL[4][4][64];   // 4KB
  int t = threadIdx.x, w = t >> 6, lane = t & 63;
  float Wreg[64];  // W[k, w*64 + lane]
#pragma unroll
  for (int k = 0; k < 64; ++k) Wreg[k] = W[(size_t)k * 256 + w * 64 + lane];
  float bv = bias[lane];
  int ngroups = (N + 3) >> 2;
  for (int g = blockIdx.x; g < ngroups; g += gridDim.x) {
    int n0 = g * 4;
    __syncthreads();
    {
      int nn = n0 + w;
      if (nn < N)
        *(float4*)&aggL[w][(t & 63) * 4] =
            *(const float4*)&agg[(size_t)nn * 256 + (t & 63) * 4];
      else
        *(float4*)&aggL[w][(t & 63) * 4] = make_float4(0.f, 0.f, 0.f, 0.f);
    }
    __syncthreads();
    float acc0 = 0.f, acc1 = 0.f, acc2 = 0.f, acc3 = 0.f;
#pragma unroll
    for (int k4 = 0; k4 < 16; ++k4) {
      float4 av0 = *(const float4*)&aggL[0][w * 64 + k4 * 4];
      float4 av1 = *(const float4*)&aggL[1][w * 64 + k4 * 4];
      float4 av2 = *(const float4*)&aggL[2][w * 64 + k4 * 4];
      float4 av3 = *(const float4*)&aggL[3][w * 64 + k4 * 4];
      float w0 = Wreg[k4 * 4 + 0], w1 = Wreg[k4 * 4 + 1];
      float w2 = Wreg[k4 * 4 + 2], w3 = Wreg[k4 * 4 + 3];
      acc0 = fmaf(av0.x, w0, acc0); acc0 = fmaf(av0.y, w1, acc0);
      acc0 = fmaf(av0.z, w2, acc0); acc0 = fmaf(av0.w, w3, acc0);
      acc1 = fmaf(av1.x, w0, acc1); acc1 = fmaf(av1.y, w1, acc1);
      acc1 = fmaf(av1.z, w2, acc1); acc1 = fmaf(av1.w, w3, acc1);
      acc2 = fmaf(av2.x, w0, acc2); acc2 = fmaf(av2.y, w1, acc2);
      acc2 = fmaf(av2.z, w2, acc2); acc2 = fmaf(av2.w, w3, acc2);
      acc3 = fmaf(av3.x, w0, acc3); acc3 = fmaf(av3.y, w1, acc3);
      acc3 = fmaf(av3.z, w2, acc3); acc3 = fmaf(av3.w, w3, acc3);
    }
    pL[w][0][lane] = acc0;
    pL[w][1][lane] = acc1;
    pL[w][2][lane] = acc2;
    pL[w][3][lane] = acc3;
    __syncthreads();
    int nn = n0 + w;
    if (nn < N) {
      out[(size_t)nn * 64 + lane] = pL[0][w][lane] + pL[1][w][lane] +
                                    pL[2][w][lane] + pL[3][w][lane] + bv;
    }
  }
}

// ---- Fused fallback (r6-proven, f32 x) used only if ws_size is too small.
__global__ __launch_bounds__(256) void gatout_kernel(
    const int* __restrict__ srt, const int* __restrict__ row,
    const float4* __restrict__ asrc4, const float4* __restrict__ adst4,
    const float* __restrict__ x, const float* __restrict__ W,
    const float* __restrict__ bias, float* __restrict__ out, int N) {
  __shared__ float4 smem4[320];
  float4 (*alL)[MAXDEG] = (float4(*)[MAXDEG])smem4;
  int (*slL)[MAXDEG] = (int(*)[MAXDEG])(smem4 + 256);
  float (*buf)[4][64] = (float(*)[4][64])smem4;
  int t = threadIdx.x, w = t >> 6, lane = t & 63;
  float Wreg[64];
#pragma unroll
  for (int k = 0; k < 64; ++k) Wreg[k] = W[(size_t)k * 256 + w * 64 + lane];
  float bv = bias[lane];
  int ngroups = (N + 3) >> 2;
  for (int g = blockIdx.x; g < ngroups; g += gridDim.x) {
    int n = g * 4 + w;
    float a0 = 0.f, a1 = 0.f, a2 = 0.f, a3 = 0.f;
    float r0 = 0.f, r1 = 0.f, r2 = 0.f, r3 = 0.f;
    __syncthreads();
    if (n < N) {
      int start = row[n], end = row[n + 1];
      int deg = end - start;
      float4 ad = adst4[n];
      float t0 = 0.f, t1 = 0.f, t2 = 0.f, t3 = 0.f;
      if (deg <= MAXDEG) {
        for (int b = 0; b < deg; b += 64) {
          if (b + lane < deg) {
            int sl = srt[start + b + lane];
            float4 as = asrc4[sl];
            float4 e;
            e.x = __expf(lrelu(as.x + ad.x));
            e.y = __expf(lrelu(as.y + ad.y));
            e.z = __expf(lrelu(as.z + ad.z));
            e.w = __expf(lrelu(as.w + ad.w));
            alL[w][b + lane] = e;
            slL[w][b + lane] = sl;
            t0 += e.x; t1 += e.y; t2 += e.z; t3 += e.w;
          }
        }
      } else {
        for (int b = start; b < end; b += 64) {
          int idx = b + lane;
          if (idx < end) {
            int sl = srt[idx];
            float4 as = asrc4[sl];
            t0 += __expf(lrelu(as.x + ad.x));
            t1 += __expf(lrelu(as.y + ad.y));
            t2 += __expf(lrelu(as.z + ad.z));
            t3 += __expf(lrelu(as.w + ad.w));
          }
        }
      }
#pragma unroll
      for (int m = 1; m < 64; m <<= 1) {
        t0 += __shfl_xor(t0, m, 64);
        t1 += __shfl_xor(t1, m, 64);
        t2 += __shfl_xor(t2, m, 64);
        t3 += __shfl_xor(t3, m, 64);
      }
      r0 = 0.25f / (t0 + 1e-16f); r1 = 0.25f / (t1 + 1e-16f);
      r2 = 0.25f / (t2 + 1e-16f); r3 = 0.25f / (t3 + 1e-16f);
      if (deg <= MAXDEG) {
        int j = 0;
        for (; j + 4 <= deg; j += 4) {
          float4 e0 = alL[w][j], e1 = alL[w][j + 1], e2 = alL[w][j + 2], e3 = alL[w][j + 3];
          int q0 = slL[w][j], q1 = slL[w][j + 1], q2 = slL[w][j + 2], q3 = slL[w][j + 3];
          float v0 = x[(size_t)q0 * 64 + lane];
          float v1 = x[(size_t)q1 * 64 + lane];
          float v2 = x[(size_t)q2 * 64 + lane];
          float v3 = x[(size_t)q3 * 64 + lane];
          a0 = fmaf(e0.x, v0, a0); a1 = fmaf(e0.y, v0, a1);
          a2 = fmaf(e0.z, v0, a2); a3 = fmaf(e0.w, v0, a3);
          a0 = fmaf(e1.x, v1, a0); a1 = fmaf(e1.y, v1, a1);
          a2 = fmaf(e1.z, v1, a2); a3 = fmaf(e1.w, v1, a3);
          a0 = fmaf(e2.x, v2, a0); a1 = fmaf(e2.y, v2, a1);
          a2 = fmaf(e2.z, v2, a2); a3 = fmaf(e2.w, v2, a3);
          a0 = fmaf(e3.x, v3, a0); a1 = fmaf(e3.y, v3, a1);
          a2 = fmaf(e3.z, v3, a2); a3 = fmaf(e3.w, v3, a3);
        }
        for (; j < deg; ++j) {
          float4 e0 = alL[w][j];
          int q0 = slL[w][j];
          float v0 = x[(size_t)q0 * 64 + lane];
          a0 = fmaf(e0.x, v0, a0); a1 = fmaf(e0.y, v0, a1);
          a2 = fmaf(e0.z, v0, a2); a3 = fmaf(e0.w, v0, a3);
        }
      } else {
        for (int b = start; b < end; b += 64) {
          int cnt = end - b;
          if (cnt > 64) cnt = 64;
          int idx = b + lane;
          int sl = 0;
          float e0 = 0.f, e1 = 0.f, e2 = 0.f, e3 = 0.f;
          if (idx < end) {
            sl = srt[idx];
            float4 as = asrc4[sl];
            e0 = __expf(lrelu(as.x + ad.x));
            e1 = __expf(lrelu(as.y + ad.y));
            e2 = __expf(lrelu(as.z + ad.z));
            e3 = __expf(lrelu(as.w + ad.w));
          }
          for (int j = 0; j < cnt; ++j) {
            int sj = __shfl(sl, j, 64);
            float b0 = __shfl(e0, j, 64), b1 = __shfl(e1, j, 64);
            float b2 = __shfl(e2, j, 64), b3 = __shfl(e3, j, 64);
            float v = x[(size_t)sj * 64 + lane];
            a0 = fmaf(b0, v, a0); a1 = fmaf(b1, v, a1);
            a2 = fmaf(b2, v, a2); a3 = fmaf(b3, v, a3);
          }
        }
      }
    }
    __syncthreads();
    buf[w][0][lane] = a0 * r0;
    buf[w][1][lane] = a1 * r1;
    buf[w][2][lane] = a2 * r2;
    buf[w][3][lane] = a3 * r3;
    __syncthreads();
    float acc0 = 0.f, acc1 = 0.f, acc2 = 0.f, acc3 = 0.f;
#pragma unroll
    for (int k4 = 0; k4 < 16; ++k4) {
      float4 av0 = *(const float4*)&buf[0][w][k4 * 4];
      float4 av1 = *(const float4*)&buf[1][w][k4 * 4];
      float4 av2 = *(const float4*)&buf[2][w][k4 * 4];
      float4 av3 = *(const float4*)&buf[3][w][k4 * 4];
      float w0 = Wreg[k4 * 4 + 0], w1 = Wreg[k4 * 4 + 1];
      float w2 = Wreg[k4 * 4 + 2], w3 = Wreg[k4 * 4 + 3];
      acc0 = fmaf(av0.x, w0, acc0); acc0 = fmaf(av0.y, w1, acc0);
      acc0 = fmaf(av0.z, w2, acc0); acc0 = fmaf(av0.w, w3, acc0);
      acc1 = fmaf(av1.x, w0, acc1); acc1 = fmaf(av1.y, w1, acc1);
      acc1 = fmaf(av1.z, w2, acc1); acc1 = fmaf(av1.w, w3, acc1);
      acc2 = fmaf(av2.x, w0, acc2); acc2 = fmaf(av2.y, w1, acc2);
      acc2 = fmaf(av2.z, w2, acc2); acc2 = fmaf(av2.w, w3, acc2);
      acc3 = fmaf(av3.x, w0, acc3); acc3 = fmaf(av3.y, w1, acc3);
      acc3 = fmaf(av3.z, w2, acc3); acc3 = fmaf(av3.w, w3, acc3);
    }
    __syncthreads();
    buf[w][0][lane] = acc0;
    buf[w][1][lane] = acc1;
    buf[w][2][lane] = acc2;
    buf[w][3][lane] = acc3;
    __syncthreads();
    if (n < N) {
      out[(size_t)n * 64 + lane] = buf[0][w][lane] + buf[1][w][lane] +
                                   buf[2][w][lane] + buf[3][w][lane] + bv;
    }
  }
}

extern "C" void kernel_launch(void* const* d_in, const int* in_sizes, int n_in,
                              void* d_out, int out_size, void* d_ws, size_t ws_size,
                              hipStream_t stream) {
  const float* meta_x = (const float*)d_in[0];
  const int* ei = (const int*)d_in[1];  // int32 edge index [2,E] flat
  const float* W = (const float*)d_in[2];
  const float* att_src = (const float*)d_in[3];
  const float* att_dst = (const float*)d_in[4];
  const float* bias = (const float*)d_in[5];
  float* out = (float*)d_out;

  int N = in_sizes[0] / 64;
  int E = in_sizes[1] / 2;
  int ET = E + N;

  char* ws = (char*)d_ws;
  size_t off = 0;
  auto alloc = [&](size_t bytes) {
    size_t o = off;
    off += (bytes + 255) & ~(size_t)255;
    return o;
  };
  size_t o_wsrc = alloc(64 * 4 * sizeof(float));
  size_t o_wdst = alloc(64 * 4 * sizeof(float));
  size_t o_asrc = alloc((size_t)N * 4 * sizeof(float));
  size_t o_adst = alloc((size_t)N * 4 * sizeof(float));
  size_t o_cnt = alloc(((size_t)N + 4) * sizeof(int));  // padded to int4 multiple
  size_t o_row = alloc(((size_t)N + 1) * sizeof(int));
  size_t o_cur = alloc((size_t)N * sizeof(int));
  size_t o_srt = alloc((size_t)ET * sizeof(int));
  size_t o_ts = alloc((((size_t)N + 255) / 256) * sizeof(int));
  size_t o_xh = alloc((size_t)N * 64 * sizeof(__hip_bfloat16));  // 6.4 MB
  size_t o_agg = alloc((size_t)N * 256 * sizeof(float));         // 51.2 MB
  bool split = (ws_size >= off);

  float* wsrc = (float*)(ws + o_wsrc);
  float* wdst = (float*)(ws + o_wdst);
  float4* asrc4 = (float4*)(ws + o_asrc);
  float4* adst4 = (float4*)(ws + o_adst);
  int* cnt = (int*)(ws + o_cnt);
  int* row = (int*)(ws + o_row);
  int* cur = (int*)(ws + o_cur);
  int* srt = (int*)(ws + o_srt);
  int* tsum = (int*)(ws + o_ts);
  __hip_bfloat16* xh = (__hip_bfloat16*)(ws + o_xh);
  float* aggp = (float*)(ws + o_agg);

  // own zero kernel instead of hipMemsetAsync (rocclr fill ran at 5 GB/s, 44 us)
  int n4 = (N + 3) >> 2;
  zero_kernel<<<(n4 + 255) / 256, 256, 0, stream>>>((int4*)cnt, n4);

  patt_kernel<<<1, 256, 0, stream>>>(W, att_src, att_dst, wsrc, wdst);
  nattn_kernel<<<(N + 3) / 4, 256, 0, stream>>>(meta_x, (const float4*)wsrc,
                                                (const float4*)wdst, asrc4, adst4, xh, N);
  if ((E & 3) == 0) {
    int nt4 = (E >> 2) + N;
    hist4_kernel<<<(nt4 + 255) / 256, 256, 0, stream>>>(ei, cnt, E, N);
  } else {
    hist_kernel<<<(ET + 255) / 256, 256, 0, stream>>>(ei, cnt, E, N);
  }
  int ntiles = (N + 255) / 256;
  scanA_kernel<<<ntiles, 256, 0, stream>>>(cnt, tsum, N);
  scanB_kernel<<<1, 256, 0, stream>>>(tsum, ntiles);
  scanC_kernel<<<ntiles, 256, 0, stream>>>(cnt, tsum, row, cur, N);
  if ((E & 3) == 0) {
    scatter8_kernel<<<2048, 256, 0, stream>>>(ei, cur, srt, E, N);
  } else {
    scatter_kernel<<<(ET + 255) / 256, 256, 0, stream>>>(ei, cur, srt, E, N);
  }
  if (split) {
    agg_kernel<<<(N + 3) / 4, 256, 0, stream>>>(srt, row, asrc4, adst4, xh, aggp, N);
    int ngroups = (N + 3) / 4;
    int pgrid = ngroups < 2048 ? ngroups : 2048;
    proj_kernel<<<pgrid, 256, 0, stream>>>(aggp, W, bias, out, N);
  } else {
    int ngroups = (N + 3) / 4;
    int ggrid = ngroups < 2048 ? ngroups : 2048;
    gatout_kernel<<<ggrid, 256, 0, stream>>>(srt, row, asrc4, adst4, meta_x, W, bias, out, N);
  }
}

// Round 13
// 186.024 us; speedup vs baseline: 1.0399x; 1.0399x over previous
//
#include <hip/hip_runtime.h>
#include <hip/hip_bf16.h>
#include <math.h>

#define MAXDEG 64

__device__ __forceinline__ float lrelu(float v) { return v > 0.0f ? v : 0.2f * v; }

// ---- prep: zero cnt (all blocks) + fold attention vecs into W (block 0 only)
__global__ void prep_kernel(int4* __restrict__ cnt4, int n4,
                            const float* __restrict__ W, const float* __restrict__ att_src,
                            const float* __restrict__ att_dst, float* __restrict__ wsrc,
                            float* __restrict__ wdst) {
  int idx = blockIdx.x * 256 + threadIdx.x;
  for (int i = idx; i < n4; i += gridDim.x * 256) cnt4[i] = make_int4(0, 0, 0, 0);
  if (blockIdx.x == 0) {
    int t = threadIdx.x;  // h = t>>6, k = t&63
    int h = t >> 6, k = t & 63;
    const float* wrow = W + (size_t)k * 256 + h * 64;
    const float* as = att_src + h * 64;
    const float* ad = att_dst + h * 64;
    float ss = 0.f, sd = 0.f;
#pragma unroll
    for (int c = 0; c < 64; ++c) {
      float w = wrow[c];
      ss = fmaf(w, as[c], ss);
      sd = fmaf(w, ad[c], sd);
    }
    wsrc[k * 4 + h] = ss;
    wdst[k * 4 + h] = sd;
  }
}

// ---- Kernel B: per-node attention scalars + bf16 copy of x (side product).
__global__ void nattn_kernel(const float* __restrict__ x, const float4* __restrict__ wsrc4,
                             const float4* __restrict__ wdst4, float4* __restrict__ asrc4,
                             float4* __restrict__ adst4, __hip_bfloat16* __restrict__ xh,
                             int N) {
  int lane = threadIdx.x & 63;
  int n = blockIdx.x * 4 + (threadIdx.x >> 6);
  if (n >= N) return;
  float xv = x[(size_t)n * 64 + lane];
  xh[(size_t)n * 64 + lane] = __float2bfloat16(xv);
  float4 ws = wsrc4[lane], wd = wdst4[lane];
  float s0 = xv * ws.x, s1 = xv * ws.y, s2 = xv * ws.z, s3 = xv * ws.w;
  float d0 = xv * wd.x, d1 = xv * wd.y, d2 = xv * wd.z, d3 = xv * wd.w;
#pragma unroll
  for (int m = 1; m < 64; m <<= 1) {
    s0 += __shfl_xor(s0, m, 64); s1 += __shfl_xor(s1, m, 64);
    s2 += __shfl_xor(s2, m, 64); s3 += __shfl_xor(s3, m, 64);
    d0 += __shfl_xor(d0, m, 64); d1 += __shfl_xor(d1, m, 64);
    d2 += __shfl_xor(d2, m, 64); d3 += __shfl_xor(d3, m, 64);
  }
  if (lane == 0) {
    asrc4[n] = make_float4(s0, s1, s2, s3);
    adst4[n] = make_float4(d0, d1, d2, d3);
  }
}

// ---- Scalar hist/scatter [round-2 proven, fallback when E%4 != 0]
__global__ void hist_kernel(const int* __restrict__ ei, int* __restrict__ counts,
                            int E, int N) {
  int e = blockIdx.x * 256 + threadIdx.x;
  int ET = E + N;
  if (e >= ET) return;
  int dst = (e < E) ? ei[(size_t)E + e] : (e - E);
  atomicAdd(&counts[dst], 1);
}

__global__ void scatter_kernel(const int* __restrict__ ei, int* __restrict__ cursor,
                               int* __restrict__ src_sorted, int E, int N) {
  int e = blockIdx.x * 256 + threadIdx.x;
  int ET = E + N;
  if (e >= ET) return;
  int src, dst;
  if (e < E) {
    src = ei[e];
    dst = ei[(size_t)E + e];
  } else {
    src = dst = e - E;
  }
  int pos = atomicAdd(&cursor[dst], 1);
  src_sorted[pos] = src;
}

// ---- int4 hist (E%4==0 path) [proven r8]
__global__ void hist4_kernel(const int* __restrict__ ei, int* __restrict__ counts,
                             int E, int N) {
  int i = blockIdx.x * 256 + threadIdx.x;
  int E4 = E >> 2;
  if (i < E4) {
    int4 d = ((const int4*)(ei + E))[i];
    atomicAdd(&counts[d.x], 1);
    atomicAdd(&counts[d.y], 1);
    atomicAdd(&counts[d.z], 1);
    atomicAdd(&counts[d.w], 1);
  } else if (i < E4 + N) {
    atomicAdd(&counts[i - E4], 1);
  }
}

// ---- XCD-sliced scatter [proven r9]
__global__ void scatter8_kernel(const int* __restrict__ ei, int* __restrict__ cursor,
                                int* __restrict__ srt, int E, int N) {
  int slice = blockIdx.x & 7;
  int bid = blockIdx.x >> 3;
  int nb = gridDim.x >> 3;
  int chunk = (N + 7) >> 3;
  int lo = slice * chunk;
  int hi = lo + chunk; if (hi > N) hi = N;
  int E4 = E >> 2;
  const int4* s4p = (const int4*)ei;
  const int4* d4p = (const int4*)(ei + E);
  int stride = nb * 256;
  for (int i = bid * 256 + threadIdx.x; i < E4; i += stride) {
    int4 d4 = d4p[i];
    bool bx = (d4.x >= lo && d4.x < hi), by = (d4.y >= lo && d4.y < hi);
    bool bz = (d4.z >= lo && d4.z < hi), bw = (d4.w >= lo && d4.w < hi);
    if (!(bx || by || bz || bw)) continue;
    int4 s4 = s4p[i];
    if (bx) { int p = atomicAdd(&cursor[d4.x], 1); srt[p] = s4.x; }
    if (by) { int p = atomicAdd(&cursor[d4.y], 1); srt[p] = s4.y; }
    if (bz) { int p = atomicAdd(&cursor[d4.z], 1); srt[p] = s4.z; }
    if (bw) { int p = atomicAdd(&cursor[d4.w], 1); srt[p] = s4.w; }
  }
  for (int n = lo + bid * 256 + threadIdx.x; n < hi; n += stride) {
    int p = atomicAdd(&cursor[n], 1);
    srt[p] = n;
  }
}

// ---- scanA: per-tile (256 counts) sums [proven r5]
__global__ void scanA_kernel(const int* __restrict__ cnt, int* __restrict__ tsum, int N) {
  int b = blockIdx.x, t = threadIdx.x;
  int idx = b * 256 + t;
  int v = (idx < N) ? cnt[idx] : 0;
#pragma unroll
  for (int m = 1; m < 64; m <<= 1) v += __shfl_xor(v, m, 64);
  __shared__ int ws[4];
  if ((t & 63) == 0) ws[t >> 6] = v;
  __syncthreads();
  if (t == 0) tsum[b] = ws[0] + ws[1] + ws[2] + ws[3];
}

// ---- scanBC (ntiles<=256): each block scans tsum itself, then intra-tile scan.
__global__ void scanBC_kernel(const int* __restrict__ cnt, const int* __restrict__ tsum,
                              int* __restrict__ row, int* __restrict__ cur, int N,
                              int ntiles) {
  __shared__ int tl[256];
  __shared__ int part[256];
  int b = blockIdx.x, t = threadIdx.x;
  // 1) block-local inclusive scan of tile sums (ntiles <= 256)
  int tv = (t < ntiles) ? tsum[t] : 0;
  tl[t] = tv;
  __syncthreads();
  for (int d = 1; d < 256; d <<= 1) {
    int u = (t >= d) ? tl[t - d] : 0;
    __syncthreads();
    tl[t] += u;
    __syncthreads();
  }
  int tileoff = (b == 0) ? 0 : tl[b - 1];
  // 2) intra-tile exclusive scan (r5-proven scanC body)
  int idx = b * 256 + t;
  int c = (idx < N) ? cnt[idx] : 0;
  part[t] = c;
  __syncthreads();
  for (int d = 1; d < 256; d <<= 1) {
    int u = (t >= d) ? part[t - d] : 0;
    __syncthreads();
    part[t] += u;
    __syncthreads();
  }
  int exc = part[t] - c + tileoff;
  if (idx < N) {
    row[idx] = exc;
    cur[idx] = exc;
    if (idx == N - 1) row[N] = exc + c;
  }
}

// ---- scanB/scanC fallback for ntiles > 256 [proven r5]
__global__ void scanB_kernel(int* __restrict__ tsum, int ntiles) {
  __shared__ int part[256];
  int t = threadIdx.x;
  int carry = 0;
  for (int b0 = 0; b0 < ntiles; b0 += 256) {
    int idx = b0 + t;
    int v = (idx < ntiles) ? tsum[idx] : 0;
    part[t] = v;
    __syncthreads();
    for (int d = 1; d < 256; d <<= 1) {
      int u = (t >= d) ? part[t - d] : 0;
      __syncthreads();
      part[t] += u;
      __syncthreads();
    }
    if (idx < ntiles) tsum[idx] = part[t] - v + carry;
    carry += part[255];
    __syncthreads();
  }
}

__global__ void scanC_kernel(const int* __restrict__ cnt, const int* __restrict__ tsum,
                             int* __restrict__ row, int* __restrict__ cur, int N) {
  __shared__ int part[256];
  int b = blockIdx.x, t = threadIdx.x;
  int idx = b * 256 + t;
  int c = (idx < N) ? cnt[idx] : 0;
  part[t] = c;
  __syncthreads();
  for (int d = 1; d < 256; d <<= 1) {
    int u = (t >= d) ? part[t - d] : 0;
    __syncthreads();
    part[t] += u;
    __syncthreads();
  }
  int exc = part[t] - c + tsum[b];
  if (idx < N) {
    row[idx] = exc;
    cur[idx] = exc;
    if (idx == N - 1) row[N] = exc + c;
  }
}

// ---- Aggregation: one wave per node, zero barriers; x bf16; agg output bf16.
__global__ __launch_bounds__(256) void agg_kernel(
    const int* __restrict__ srt, const int* __restrict__ row,
    const float4* __restrict__ asrc4, const float4* __restrict__ adst4,
    const __hip_bfloat16* __restrict__ xh, __hip_bfloat16* __restrict__ agg, int N) {
  __shared__ float4 alL[4][MAXDEG];  // 4096B
  __shared__ int slL[4][MAXDEG];     // 1024B
  int t = threadIdx.x, w = t >> 6, lane = t & 63;
  int n = blockIdx.x * 4 + w;
  if (n >= N) return;
  int start = row[n], end = row[n + 1];
  int deg = end - start;
  float4 ad = adst4[n];
  float t0 = 0.f, t1 = 0.f, t2 = 0.f, t3 = 0.f;
  if (deg <= MAXDEG) {
    for (int b = 0; b < deg; b += 64) {
      if (b + lane < deg) {
        int sl = srt[start + b + lane];
        float4 as = asrc4[sl];
        float4 e;
        e.x = __expf(lrelu(as.x + ad.x));
        e.y = __expf(lrelu(as.y + ad.y));
        e.z = __expf(lrelu(as.z + ad.z));
        e.w = __expf(lrelu(as.w + ad.w));
        alL[w][b + lane] = e;
        slL[w][b + lane] = sl;
        t0 += e.x; t1 += e.y; t2 += e.z; t3 += e.w;
      }
    }
  } else {
    for (int b = start; b < end; b += 64) {
      int idx = b + lane;
      if (idx < end) {
        int sl = srt[idx];
        float4 as = asrc4[sl];
        t0 += __expf(lrelu(as.x + ad.x));
        t1 += __expf(lrelu(as.y + ad.y));
        t2 += __expf(lrelu(as.z + ad.z));
        t3 += __expf(lrelu(as.w + ad.w));
      }
    }
  }
#pragma unroll
  for (int m = 1; m < 64; m <<= 1) {
    t0 += __shfl_xor(t0, m, 64);
    t1 += __shfl_xor(t1, m, 64);
    t2 += __shfl_xor(t2, m, 64);
    t3 += __shfl_xor(t3, m, 64);
  }
  float r0 = 0.25f / (t0 + 1e-16f), r1 = 0.25f / (t1 + 1e-16f);
  float r2 = 0.25f / (t2 + 1e-16f), r3 = 0.25f / (t3 + 1e-16f);
  float a0 = 0.f, a1 = 0.f, a2 = 0.f, a3 = 0.f;
  if (deg <= MAXDEG) {
    int j = 0;
    for (; j + 4 <= deg; j += 4) {
      float4 e0 = alL[w][j], e1 = alL[w][j + 1], e2 = alL[w][j + 2], e3 = alL[w][j + 3];
      int q0 = slL[w][j], q1 = slL[w][j + 1], q2 = slL[w][j + 2], q3 = slL[w][j + 3];
      float v0 = __bfloat162float(xh[(size_t)q0 * 64 + lane]);
      float v1 = __bfloat162float(xh[(size_t)q1 * 64 + lane]);
      float v2 = __bfloat162float(xh[(size_t)q2 * 64 + lane]);
      float v3 = __bfloat162float(xh[(size_t)q3 * 64 + lane]);
      a0 = fmaf(e0.x, v0, a0); a1 = fmaf(e0.y, v0, a1);
      a2 = fmaf(e0.z, v0, a2); a3 = fmaf(e0.w, v0, a3);
      a0 = fmaf(e1.x, v1, a0); a1 = fmaf(e1.y, v1, a1);
      a2 = fmaf(e1.z, v1, a2); a3 = fmaf(e1.w, v1, a3);
      a0 = fmaf(e2.x, v2, a0); a1 = fmaf(e2.y, v2, a1);
      a2 = fmaf(e2.z, v2, a2); a3 = fmaf(e2.w, v2, a3);
      a0 = fmaf(e3.x, v3, a0); a1 = fmaf(e3.y, v3, a1);
      a2 = fmaf(e3.z, v3, a2); a3 = fmaf(e3.w, v3, a3);
    }
    for (; j < deg; ++j) {
      float4 e0 = alL[w][j];
      int q0 = slL[w][j];
      float v0 = __bfloat162float(xh[(size_t)q0 * 64 + lane]);
      a0 = fmaf(e0.x, v0, a0); a1 = fmaf(e0.y, v0, a1);
      a2 = fmaf(e0.z, v0, a2); a3 = fmaf(e0.w, v0, a3);
    }
  } else {
    for (int b = start; b < end; b += 64) {
      int cnt = end - b;
      if (cnt > 64) cnt = 64;
      int idx = b + lane;
      int sl = 0;
      float e0 = 0.f, e1 = 0.f, e2 = 0.f, e3 = 0.f;
      if (idx < end) {
        sl = srt[idx];
        float4 as = asrc4[sl];
        e0 = __expf(lrelu(as.x + ad.x));
        e1 = __expf(lrelu(as.y + ad.y));
        e2 = __expf(lrelu(as.z + ad.z));
        e3 = __expf(lrelu(as.w + ad.w));
      }
      for (int j = 0; j < cnt; ++j) {
        int sj = __shfl(sl, j, 64);
        float b0 = __shfl(e0, j, 64), b1 = __shfl(e1, j, 64);
        float b2 = __shfl(e2, j, 64), b3 = __shfl(e3, j, 64);
        float v = __bfloat162float(xh[(size_t)sj * 64 + lane]);
        a0 = fmaf(b0, v, a0); a1 = fmaf(b1, v, a1);
        a2 = fmaf(b2, v, a2); a3 = fmaf(b3, v, a3);
      }
    }
  }
  __hip_bfloat16* ao = agg + (size_t)n * 256;
  ao[lane] = __float2bfloat16(a0 * r0);
  ao[64 + lane] = __float2bfloat16(a1 * r1);
  ao[128 + lane] = __float2bfloat16(a2 * r2);
  ao[192 + lane] = __float2bfloat16(a3 * r3);
}

// ---- Projection: reads bf16 agg, stages as f32 in LDS [r8 arithmetic]
__global__ __launch_bounds__(256) void proj_kernel(
    const __hip_bfloat16* __restrict__ agg, const float* __restrict__ W,
    const float* __restrict__ bias, float* __restrict__ out, int N) {
  __shared__ float aggL[4][256];   // 4KB
  __shared__ float pL[4][4][64];   // 4KB
  int t = threadIdx.x, w = t >> 6, lane = t & 63;
  float Wreg[64];  // W[k, w*64 + lane]
#pragma unroll
  for (int k = 0; k < 64; ++k) Wreg[k] = W[(size_t)k * 256 + w * 64 + lane];
  float bv = bias[lane];
  int ngroups = (N + 3) >> 2;
  for (int g = blockIdx.x; g < ngroups; g += gridDim.x) {
    int n0 = g * 4;
    __syncthreads();
    {
      int nn = n0 + w;
      if (nn < N) {
        ushort4 u = ((const ushort4*)(agg + (size_t)nn * 256))[t & 63];
        float4 f;
        f.x = __bfloat162float(*(__hip_bfloat16*)&u.x);
        f.y = __bfloat162float(*(__hip_bfloat16*)&u.y);
        f.z = __bfloat162float(*(__hip_bfloat16*)&u.z);
        f.w = __bfloat162float(*(__hip_bfloat16*)&u.w);
        *(float4*)&aggL[w][(t & 63) * 4] = f;
      } else {
        *(float4*)&aggL[w][(t & 63) * 4] = make_float4(0.f, 0.f, 0.f, 0.f);
      }
    }
    __syncthreads();
    float acc0 = 0.f, acc1 = 0.f, acc2 = 0.f, acc3 = 0.f;
#pragma unroll
    for (int k4 = 0; k4 < 16; ++k4) {
      float4 av0 = *(const float4*)&aggL[0][w * 64 + k4 * 4];
      float4 av1 = *(const float4*)&aggL[1][w * 64 + k4 * 4];
      float4 av2 = *(const float4*)&aggL[2][w * 64 + k4 * 4];
      float4 av3 = *(const float4*)&aggL[3][w * 64 + k4 * 4];
      float w0 = Wreg[k4 * 4 + 0], w1 = Wreg[k4 * 4 + 1];
      float w2 = Wreg[k4 * 4 + 2], w3 = Wreg[k4 * 4 + 3];
      acc0 = fmaf(av0.x, w0, acc0); acc0 = fmaf(av0.y, w1, acc0);
      acc0 = fmaf(av0.z, w2, acc0); acc0 = fmaf(av0.w, w3, acc0);
      acc1 = fmaf(av1.x, w0, acc1); acc1 = fmaf(av1.y, w1, acc1);
      acc1 = fmaf(av1.z, w2, acc1); acc1 = fmaf(av1.w, w3, acc1);
      acc2 = fmaf(av2.x, w0, acc2); acc2 = fmaf(av2.y, w1, acc2);
      acc2 = fmaf(av2.z, w2, acc2); acc2 = fmaf(av2.w, w3, acc2);
      acc3 = fmaf(av3.x, w0, acc3); acc3 = fmaf(av3.y, w1, acc3);
      acc3 = fmaf(av3.z, w2, acc3); acc3 = fmaf(av3.w, w3, acc3);
    }
    pL[w][0][lane] = acc0;
    pL[w][1][lane] = acc1;
    pL[w][2][lane] = acc2;
    pL[w][3][lane] = acc3;
    __syncthreads();
    int nn = n0 + w;
    if (nn < N) {
      out[(size_t)nn * 64 + lane] = pL[0][w][lane] + pL[1][w][lane] +
                                    pL[2][w][lane] + pL[3][w][lane] + bv;
    }
  }
}

// ---- Fused fallback (r6-proven, f32 x) used only if ws_size is too small.
__global__ __launch_bounds__(256) void gatout_kernel(
    const int* __restrict__ srt, const int* __restrict__ row,
    const float4* __restrict__ asrc4, const float4* __restrict__ adst4,
    const float* __restrict__ x, const float* __restrict__ W,
    const float* __restrict__ bias, float* __restrict__ out, int N) {
  __shared__ float4 smem4[320];
  float4 (*alL)[MAXDEG] = (float4(*)[MAXDEG])smem4;
  int (*slL)[MAXDEG] = (int(*)[MAXDEG])(smem4 + 256);
  float (*buf)[4][64] = (float(*)[4][64])smem4;
  int t = threadIdx.x, w = t >> 6, lane = t & 63;
  float Wreg[64];
#pragma unroll
  for (int k = 0; k < 64; ++k) Wreg[k] = W[(size_t)k * 256 + w * 64 + lane];
  float bv = bias[lane];
  int ngroups = (N + 3) >> 2;
  for (int g = blockIdx.x; g < ngroups; g += gridDim.x) {
    int n = g * 4 + w;
    float a0 = 0.f, a1 = 0.f, a2 = 0.f, a3 = 0.f;
    float r0 = 0.f, r1 = 0.f, r2 = 0.f, r3 = 0.f;
    __syncthreads();
    if (n < N) {
      int start = row[n], end = row[n + 1];
      int deg = end - start;
      float4 ad = adst4[n];
      float t0 = 0.f, t1 = 0.f, t2 = 0.f, t3 = 0.f;
      if (deg <= MAXDEG) {
        for (int b = 0; b < deg; b += 64) {
          if (b + lane < deg) {
            int sl = srt[start + b + lane];
            float4 as = asrc4[sl];
            float4 e;
            e.x = __expf(lrelu(as.x + ad.x));
            e.y = __expf(lrelu(as.y + ad.y));
            e.z = __expf(lrelu(as.z + ad.z));
            e.w = __expf(lrelu(as.w + ad.w));
            alL[w][b + lane] = e;
            slL[w][b + lane] = sl;
            t0 += e.x; t1 += e.y; t2 += e.z; t3 += e.w;
          }
        }
      } else {
        for (int b = start; b < end; b += 64) {
          int idx = b + lane;
          if (idx < end) {
            int sl = srt[idx];
            float4 as = asrc4[sl];
            t0 += __expf(lrelu(as.x + ad.x));
            t1 += __expf(lrelu(as.y + ad.y));
            t2 += __expf(lrelu(as.z + ad.z));
            t3 += __expf(lrelu(as.w + ad.w));
          }
        }
      }
#pragma unroll
      for (int m = 1; m < 64; m <<= 1) {
        t0 += __shfl_xor(t0, m, 64);
        t1 += __shfl_xor(t1, m, 64);
        t2 += __shfl_xor(t2, m, 64);
        t3 += __shfl_xor(t3, m, 64);
      }
      r0 = 0.25f / (t0 + 1e-16f); r1 = 0.25f / (t1 + 1e-16f);
      r2 = 0.25f / (t2 + 1e-16f); r3 = 0.25f / (t3 + 1e-16f);
      if (deg <= MAXDEG) {
        int j = 0;
        for (; j + 4 <= deg; j += 4) {
          float4 e0 = alL[w][j], e1 = alL[w][j + 1], e2 = alL[w][j + 2], e3 = alL[w][j + 3];
          int q0 = slL[w][j], q1 = slL[w][j + 1], q2 = slL[w][j + 2], q3 = slL[w][j + 3];
          float v0 = x[(size_t)q0 * 64 + lane];
          float v1 = x[(size_t)q1 * 64 + lane];
          float v2 = x[(size_t)q2 * 64 + lane];
          float v3 = x[(size_t)q3 * 64 + lane];
          a0 = fmaf(e0.x, v0, a0); a1 = fmaf(e0.y, v0, a1);
          a2 = fmaf(e0.z, v0, a2); a3 = fmaf(e0.w, v0, a3);
          a0 = fmaf(e1.x, v1, a0); a1 = fmaf(e1.y, v1, a1);
          a2 = fmaf(e1.z, v1, a2); a3 = fmaf(e1.w, v1, a3);
          a0 = fmaf(e2.x, v2, a0); a1 = fmaf(e2.y, v2, a1);
          a2 = fmaf(e2.z, v2, a2); a3 = fmaf(e2.w, v2, a3);
          a0 = fmaf(e3.x, v3, a0); a1 = fmaf(e3.y, v3, a1);
          a2 = fmaf(e3.z, v3, a2); a3 = fmaf(e3.w, v3, a3);
        }
        for (; j < deg; ++j) {
          float4 e0 = alL[w][j];
          int q0 = slL[w][j];
          float v0 = x[(size_t)q0 * 64 + lane];
          a0 = fmaf(e0.x, v0, a0); a1 = fmaf(e0.y, v0, a1);
          a2 = fmaf(e0.z, v0, a2); a3 = fmaf(e0.w, v0, a3);
        }
      } else {
        for (int b = start; b < end; b += 64) {
          int cnt = end - b;
          if (cnt > 64) cnt = 64;
          int idx = b + lane;
          int sl = 0;
          float e0 = 0.f, e1 = 0.f, e2 = 0.f, e3 = 0.f;
          if (idx < end) {
            sl = srt[idx];
            float4 as = asrc4[sl];
            e0 = __expf(lrelu(as.x + ad.x));
            e1 = __expf(lrelu(as.y + ad.y));
            e2 = __expf(lrelu(as.z + ad.z));
            e3 = __expf(lrelu(as.w + ad.w));
          }
          for (int j = 0; j < cnt; ++j) {
            int sj = __shfl(sl, j, 64);
            float b0 = __shfl(e0, j, 64), b1 = __shfl(e1, j, 64);
            float b2 = __shfl(e2, j, 64), b3 = __shfl(e3, j, 64);
            float v = x[(size_t)sj * 64 + lane];
            a0 = fmaf(b0, v, a0); a1 = fmaf(b1, v, a1);
            a2 = fmaf(b2, v, a2); a3 = fmaf(b3, v, a3);
          }
        }
      }
    }
    __syncthreads();
    buf[w][0][lane] = a0 * r0;
    buf[w][1][lane] = a1 * r1;
    buf[w][2][lane] = a2 * r2;
    buf[w][3][lane] = a3 * r3;
    __syncthreads();
    float acc0 = 0.f, acc1 = 0.f, acc2 = 0.f, acc3 = 0.f;
#pragma unroll
    for (int k4 = 0; k4 < 16; ++k4) {
      float4 av0 = *(const float4*)&buf[0][w][k4 * 4];
      float4 av1 = *(const float4*)&buf[1][w][k4 * 4];
      float4 av2 = *(const float4*)&buf[2][w][k4 * 4];
      float4 av3 = *(const float4*)&buf[3][w][k4 * 4];
      float w0 = Wreg[k4 * 4 + 0], w1 = Wreg[k4 * 4 + 1];
      float w2 = Wreg[k4 * 4 + 2], w3 = Wreg[k4 * 4 + 3];
      acc0 = fmaf(av0.x, w0, acc0); acc0 = fmaf(av0.y, w1, acc0);
      acc0 = fmaf(av0.z, w2, acc0); acc0 = fmaf(av0.w, w3, acc0);
      acc1 = fmaf(av1.x, w0, acc1); acc1 = fmaf(av1.y, w1, acc1);
      acc1 = fmaf(av1.z, w2, acc1); acc1 = fmaf(av1.w, w3, acc1);
      acc2 = fmaf(av2.x, w0, acc2); acc2 = fmaf(av2.y, w1, acc2);
      acc2 = fmaf(av2.z, w2, acc2); acc2 = fmaf(av2.w, w3, acc2);
      acc3 = fmaf(av3.x, w0, acc3); acc3 = fmaf(av3.y, w1, acc3);
      acc3 = fmaf(av3.z, w2, acc3); acc3 = fmaf(av3.w, w3, acc3);
    }
    __syncthreads();
    buf[w][0][lane] = acc0;
    buf[w][1][lane] = acc1;
    buf[w][2][lane] = acc2;
    buf[w][3][lane] = acc3;
    __syncthreads();
    if (n < N) {
      out[(size_t)n * 64 + lane] = buf[0][w][lane] + buf[1][w][lane] +
                                   buf[2][w][lane] + buf[3][w][lane] + bv;
    }
  }
}

extern "C" void kernel_launch(void* const* d_in, const int* in_sizes, int n_in,
                              void* d_out, int out_size, void* d_ws, size_t ws_size,
                              hipStream_t stream) {
  const float* meta_x = (const float*)d_in[0];
  const int* ei = (const int*)d_in[1];  // int32 edge index [2,E] flat
  const float* W = (const float*)d_in[2];
  const float* att_src = (const float*)d_in[3];
  const float* att_dst = (const float*)d_in[4];
  const float* bias = (const float*)d_in[5];
  float* out = (float*)d_out;

  int N = in_sizes[0] / 64;
  int E = in_sizes[1] / 2;
  int ET = E + N;

  char* ws = (char*)d_ws;
  size_t off = 0;
  auto alloc = [&](size_t bytes) {
    size_t o = off;
    off += (bytes + 255) & ~(size_t)255;
    return o;
  };
  size_t o_wsrc = alloc(64 * 4 * sizeof(float));
  size_t o_wdst = alloc(64 * 4 * sizeof(float));
  size_t o_asrc = alloc((size_t)N * 4 * sizeof(float));
  size_t o_adst = alloc((size_t)N * 4 * sizeof(float));
  size_t o_cnt = alloc(((size_t)N + 4) * sizeof(int));  // padded to int4 multiple
  size_t o_row = alloc(((size_t)N + 1) * sizeof(int));
  size_t o_cur = alloc((size_t)N * sizeof(int));
  size_t o_srt = alloc((size_t)ET * sizeof(int));
  size_t o_ts = alloc((((size_t)N + 255) / 256) * sizeof(int));
  size_t o_xh = alloc((size_t)N * 64 * sizeof(__hip_bfloat16));   // 6.4 MB
  size_t o_agg = alloc((size_t)N * 256 * sizeof(__hip_bfloat16)); // 25.6 MB
  bool split = (ws_size >= off);

  float* wsrc = (float*)(ws + o_wsrc);
  float* wdst = (float*)(ws + o_wdst);
  float4* asrc4 = (float4*)(ws + o_asrc);
  float4* adst4 = (float4*)(ws + o_adst);
  int* cnt = (int*)(ws + o_cnt);
  int* row = (int*)(ws + o_row);
  int* cur = (int*)(ws + o_cur);
  int* srt = (int*)(ws + o_srt);
  int* tsum = (int*)(ws + o_ts);
  __hip_bfloat16* xh = (__hip_bfloat16*)(ws + o_xh);
  __hip_bfloat16* aggp = (__hip_bfloat16*)(ws + o_agg);

  int n4 = (N + 4) >> 2;
  prep_kernel<<<64, 256, 0, stream>>>((int4*)cnt, n4, W, att_src, att_dst, wsrc, wdst);
  nattn_kernel<<<(N + 3) / 4, 256, 0, stream>>>(meta_x, (const float4*)wsrc,
                                                (const float4*)wdst, asrc4, adst4, xh, N);
  if ((E & 3) == 0) {
    int nt4 = (E >> 2) + N;
    hist4_kernel<<<(nt4 + 255) / 256, 256, 0, stream>>>(ei, cnt, E, N);
  } else {
    hist_kernel<<<(ET + 255) / 256, 256, 0, stream>>>(ei, cnt, E, N);
  }
  int ntiles = (N + 255) / 256;
  scanA_kernel<<<ntiles, 256, 0, stream>>>(cnt, tsum, N);
  if (ntiles <= 256) {
    scanBC_kernel<<<ntiles, 256, 0, stream>>>(cnt, tsum, row, cur, N, ntiles);
  } else {
    scanB_kernel<<<1, 256, 0, stream>>>(tsum, ntiles);
    scanC_kernel<<<ntiles, 256, 0, stream>>>(cnt, tsum, row, cur, N);
  }
  if ((E & 3) == 0) {
    scatter8_kernel<<<2048, 256, 0, stream>>>(ei, cur, srt, E, N);
  } else {
    scatter_kernel<<<(ET + 255) / 256, 256, 0, stream>>>(ei, cur, srt, E, N);
  }
  if (split) {
    agg_kernel<<<(N + 3) / 4, 256, 0, stream>>>(srt, row, asrc4, adst4, xh, aggp, N);
    int ngroups = (N + 3) / 4;
    int pgrid = ngroups < 2048 ? ngroups : 2048;
    proj_kernel<<<pgrid, 256, 0, stream>>>(aggp, W, bias, out, N);
  } else {
    int ngroups = (N + 3) / 4;
    int ggrid = ngroups < 2048 ? ngroups : 2048;
    gatout_kernel<<<ggrid, 256, 0, stream>>>(srt, row, asrc4, adst4, meta_x, W, bias, out, N);
  }
}

// Round 14
// 185.624 us; speedup vs baseline: 1.0421x; 1.0022x over previous
//
#include <hip/hip_runtime.h>
#include <hip/hip_bf16.h>
#include <math.h>

#define MAXDEG 64

__device__ __forceinline__ float lrelu(float v) { return v > 0.0f ? v : 0.2f * v; }

// ---- prep: zero cnt incl. tile padding (all blocks) + fold att vecs (block 0)
__global__ void prep_kernel(int4* __restrict__ cnt4, int n4,
                            const float* __restrict__ W, const float* __restrict__ att_src,
                            const float* __restrict__ att_dst, float* __restrict__ wsrc,
                            float* __restrict__ wdst) {
  int idx = blockIdx.x * 256 + threadIdx.x;
  for (int i = idx; i < n4; i += gridDim.x * 256) cnt4[i] = make_int4(0, 0, 0, 0);
  if (blockIdx.x == 0) {
    int t = threadIdx.x;  // h = t>>6, k = t&63
    int h = t >> 6, k = t & 63;
    const float* wrow = W + (size_t)k * 256 + h * 64;
    const float* as = att_src + h * 64;
    const float* ad = att_dst + h * 64;
    float ss = 0.f, sd = 0.f;
#pragma unroll
    for (int c = 0; c < 64; ++c) {
      float w = wrow[c];
      ss = fmaf(w, as[c], ss);
      sd = fmaf(w, ad[c], sd);
    }
    wsrc[k * 4 + h] = ss;
    wdst[k * 4 + h] = sd;
  }
}

// ---- Fused nattn + hist4 (E%4==0 path). Blocks [0,nbh): hist; [nbh,nbh+nbn): nattn.
__global__ void nh_kernel(const float* __restrict__ x, const float4* __restrict__ wsrc4,
                          const float4* __restrict__ wdst4, float4* __restrict__ asrc4,
                          float4* __restrict__ adst4, __hip_bfloat16* __restrict__ xh,
                          const int* __restrict__ ei, int* __restrict__ counts,
                          int E, int N, int nbh) {
  if (blockIdx.x < nbh) {
    // hist4 body [proven r8]
    int i = blockIdx.x * 256 + threadIdx.x;
    int E4 = E >> 2;
    if (i < E4) {
      int4 d = ((const int4*)(ei + E))[i];
      atomicAdd(&counts[d.x], 1);
      atomicAdd(&counts[d.y], 1);
      atomicAdd(&counts[d.z], 1);
      atomicAdd(&counts[d.w], 1);
    } else if (i < E4 + N) {
      atomicAdd(&counts[i - E4], 1);
    }
    return;
  }
  // nattn body [proven r10]
  int lane = threadIdx.x & 63;
  int n = (blockIdx.x - nbh) * 4 + (threadIdx.x >> 6);
  if (n >= N) return;
  float xv = x[(size_t)n * 64 + lane];
  xh[(size_t)n * 64 + lane] = __float2bfloat16(xv);
  float4 ws = wsrc4[lane], wd = wdst4[lane];
  float s0 = xv * ws.x, s1 = xv * ws.y, s2 = xv * ws.z, s3 = xv * ws.w;
  float d0 = xv * wd.x, d1 = xv * wd.y, d2 = xv * wd.z, d3 = xv * wd.w;
#pragma unroll
  for (int m = 1; m < 64; m <<= 1) {
    s0 += __shfl_xor(s0, m, 64); s1 += __shfl_xor(s1, m, 64);
    s2 += __shfl_xor(s2, m, 64); s3 += __shfl_xor(s3, m, 64);
    d0 += __shfl_xor(d0, m, 64); d1 += __shfl_xor(d1, m, 64);
    d2 += __shfl_xor(d2, m, 64); d3 += __shfl_xor(d3, m, 64);
  }
  if (lane == 0) {
    asrc4[n] = make_float4(s0, s1, s2, s3);
    adst4[n] = make_float4(d0, d1, d2, d3);
  }
}

// ---- Standalone nattn/hist (E%4!=0 fallback) [proven]
__global__ void nattn_kernel(const float* __restrict__ x, const float4* __restrict__ wsrc4,
                             const float4* __restrict__ wdst4, float4* __restrict__ asrc4,
                             float4* __restrict__ adst4, __hip_bfloat16* __restrict__ xh,
                             int N) {
  int lane = threadIdx.x & 63;
  int n = blockIdx.x * 4 + (threadIdx.x >> 6);
  if (n >= N) return;
  float xv = x[(size_t)n * 64 + lane];
  xh[(size_t)n * 64 + lane] = __float2bfloat16(xv);
  float4 ws = wsrc4[lane], wd = wdst4[lane];
  float s0 = xv * ws.x, s1 = xv * ws.y, s2 = xv * ws.z, s3 = xv * ws.w;
  float d0 = xv * wd.x, d1 = xv * wd.y, d2 = xv * wd.z, d3 = xv * wd.w;
#pragma unroll
  for (int m = 1; m < 64; m <<= 1) {
    s0 += __shfl_xor(s0, m, 64); s1 += __shfl_xor(s1, m, 64);
    s2 += __shfl_xor(s2, m, 64); s3 += __shfl_xor(s3, m, 64);
    d0 += __shfl_xor(d0, m, 64); d1 += __shfl_xor(d1, m, 64);
    d2 += __shfl_xor(d2, m, 64); d3 += __shfl_xor(d3, m, 64);
  }
  if (lane == 0) {
    asrc4[n] = make_float4(s0, s1, s2, s3);
    adst4[n] = make_float4(d0, d1, d2, d3);
  }
}

__global__ void hist_kernel(const int* __restrict__ ei, int* __restrict__ counts,
                            int E, int N) {
  int e = blockIdx.x * 256 + threadIdx.x;
  int ET = E + N;
  if (e >= ET) return;
  int dst = (e < E) ? ei[(size_t)E + e] : (e - E);
  atomicAdd(&counts[dst], 1);
}

__global__ void scatter_kernel(const int* __restrict__ ei, int* __restrict__ cursor,
                               int* __restrict__ src_sorted, int E, int N) {
  int e = blockIdx.x * 256 + threadIdx.x;
  int ET = E + N;
  if (e >= ET) return;
  int src, dst;
  if (e < E) {
    src = ei[e];
    dst = ei[(size_t)E + e];
  } else {
    src = dst = e - E;
  }
  int pos = atomicAdd(&cursor[dst], 1);
  src_sorted[pos] = src;
}

// ---- XCD-sliced scatter [proven r9]
__global__ void scatter8_kernel(const int* __restrict__ ei, int* __restrict__ cursor,
                                int* __restrict__ srt, int E, int N) {
  int slice = blockIdx.x & 7;
  int bid = blockIdx.x >> 3;
  int nb = gridDim.x >> 3;
  int chunk = (N + 7) >> 3;
  int lo = slice * chunk;
  int hi = lo + chunk; if (hi > N) hi = N;
  int E4 = E >> 2;
  const int4* s4p = (const int4*)ei;
  const int4* d4p = (const int4*)(ei + E);
  int stride = nb * 256;
  for (int i = bid * 256 + threadIdx.x; i < E4; i += stride) {
    int4 d4 = d4p[i];
    bool bx = (d4.x >= lo && d4.x < hi), by = (d4.y >= lo && d4.y < hi);
    bool bz = (d4.z >= lo && d4.z < hi), bw = (d4.w >= lo && d4.w < hi);
    if (!(bx || by || bz || bw)) continue;
    int4 s4 = s4p[i];
    if (bx) { int p = atomicAdd(&cursor[d4.x], 1); srt[p] = s4.x; }
    if (by) { int p = atomicAdd(&cursor[d4.y], 1); srt[p] = s4.y; }
    if (bz) { int p = atomicAdd(&cursor[d4.z], 1); srt[p] = s4.z; }
    if (bw) { int p = atomicAdd(&cursor[d4.w], 1); srt[p] = s4.w; }
  }
  for (int n = lo + bid * 256 + threadIdx.x; n < hi; n += stride) {
    int p = atomicAdd(&cursor[n], 1);
    srt[p] = n;
  }
}

// ---- scanABC (ntiles<=256): each block computes ALL tile sums (int4 reads of the
// zero-padded cnt), block-scans them, then does the proven intra-tile scan.
__global__ void scanABC_kernel(const int* __restrict__ cnt, int* __restrict__ row,
                               int* __restrict__ cur, int N, int ntiles) {
  __shared__ int tl[256];
  __shared__ int part[256];
  int b = blockIdx.x, t = threadIdx.x;
  // 1) tile sums: thread t sums tile t (256 counts = 64 int4; cnt zero-padded)
  int s = 0;
  if (t < ntiles) {
    const int4* c4 = (const int4*)cnt + t * 64;
    for (int i = 0; i < 64; ++i) {
      int4 v = c4[i];
      s += v.x + v.y + v.z + v.w;
    }
  }
  tl[t] = s;
  __syncthreads();
  for (int d = 1; d < 256; d <<= 1) {
    int u = (t >= d) ? tl[t - d] : 0;
    __syncthreads();
    tl[t] += u;
    __syncthreads();
  }
  int tileoff = (b == 0) ? 0 : tl[b - 1];
  // 2) intra-tile exclusive scan [proven r5/r12]
  int idx = b * 256 + t;
  int c = (idx < N) ? cnt[idx] : 0;
  part[t] = c;
  __syncthreads();
  for (int d = 1; d < 256; d <<= 1) {
    int u = (t >= d) ? part[t - d] : 0;
    __syncthreads();
    part[t] += u;
    __syncthreads();
  }
  int exc = part[t] - c + tileoff;
  if (idx < N) {
    row[idx] = exc;
    cur[idx] = exc;
    if (idx == N - 1) row[N] = exc + c;
  }
}

// ---- scanA/B/C fallback for ntiles > 256 [proven r5]
__global__ void scanA_kernel(const int* __restrict__ cnt, int* __restrict__ tsum, int N) {
  int b = blockIdx.x, t = threadIdx.x;
  int idx = b * 256 + t;
  int v = (idx < N) ? cnt[idx] : 0;
#pragma unroll
  for (int m = 1; m < 64; m <<= 1) v += __shfl_xor(v, m, 64);
  __shared__ int ws[4];
  if ((t & 63) == 0) ws[t >> 6] = v;
  __syncthreads();
  if (t == 0) tsum[b] = ws[0] + ws[1] + ws[2] + ws[3];
}

__global__ void scanB_kernel(int* __restrict__ tsum, int ntiles) {
  __shared__ int part[256];
  int t = threadIdx.x;
  int carry = 0;
  for (int b0 = 0; b0 < ntiles; b0 += 256) {
    int idx = b0 + t;
    int v = (idx < ntiles) ? tsum[idx] : 0;
    part[t] = v;
    __syncthreads();
    for (int d = 1; d < 256; d <<= 1) {
      int u = (t >= d) ? part[t - d] : 0;
      __syncthreads();
      part[t] += u;
      __syncthreads();
    }
    if (idx < ntiles) tsum[idx] = part[t] - v + carry;
    carry += part[255];
    __syncthreads();
  }
}

__global__ void scanC_kernel(const int* __restrict__ cnt, const int* __restrict__ tsum,
                             int* __restrict__ row, int* __restrict__ cur, int N) {
  __shared__ int part[256];
  int b = blockIdx.x, t = threadIdx.x;
  int idx = b * 256 + t;
  int c = (idx < N) ? cnt[idx] : 0;
  part[t] = c;
  __syncthreads();
  for (int d = 1; d < 256; d <<= 1) {
    int u = (t >= d) ? part[t - d] : 0;
    __syncthreads();
    part[t] += u;
    __syncthreads();
  }
  int exc = part[t] - c + tsum[b];
  if (idx < N) {
    row[idx] = exc;
    cur[idx] = exc;
    if (idx == N - 1) row[N] = exc + c;
  }
}

// ---- Aggregation: one wave per node, zero barriers; bf16 x; bf16 agg [proven r13]
__global__ __launch_bounds__(256) void agg_kernel(
    const int* __restrict__ srt, const int* __restrict__ row,
    const float4* __restrict__ asrc4, const float4* __restrict__ adst4,
    const __hip_bfloat16* __restrict__ xh, __hip_bfloat16* __restrict__ agg, int N) {
  __shared__ float4 alL[4][MAXDEG];  // 4096B
  __shared__ int slL[4][MAXDEG];     // 1024B
  int t = threadIdx.x, w = t >> 6, lane = t & 63;
  int n = blockIdx.x * 4 + w;
  if (n >= N) return;
  int start = row[n], end = row[n + 1];
  int deg = end - start;
  float4 ad = adst4[n];
  float t0 = 0.f, t1 = 0.f, t2 = 0.f, t3 = 0.f;
  if (deg <= MAXDEG) {
    for (int b = 0; b < deg; b += 64) {
      if (b + lane < deg) {
        int sl = srt[start + b + lane];
        float4 as = asrc4[sl];
        float4 e;
        e.x = __expf(lrelu(as.x + ad.x));
        e.y = __expf(lrelu(as.y + ad.y));
        e.z = __expf(lrelu(as.z + ad.z));
        e.w = __expf(lrelu(as.w + ad.w));
        alL[w][b + lane] = e;
        slL[w][b + lane] = sl;
        t0 += e.x; t1 += e.y; t2 += e.z; t3 += e.w;
      }
    }
  } else {
    for (int b = start; b < end; b += 64) {
      int idx = b + lane;
      if (idx < end) {
        int sl = srt[idx];
        float4 as = asrc4[sl];
        t0 += __expf(lrelu(as.x + ad.x));
        t1 += __expf(lrelu(as.y + ad.y));
        t2 += __expf(lrelu(as.z + ad.z));
        t3 += __expf(lrelu(as.w + ad.w));
      }
    }
  }
#pragma unroll
  for (int m = 1; m < 64; m <<= 1) {
    t0 += __shfl_xor(t0, m, 64);
    t1 += __shfl_xor(t1, m, 64);
    t2 += __shfl_xor(t2, m, 64);
    t3 += __shfl_xor(t3, m, 64);
  }
  float r0 = 0.25f / (t0 + 1e-16f), r1 = 0.25f / (t1 + 1e-16f);
  float r2 = 0.25f / (t2 + 1e-16f), r3 = 0.25f / (t3 + 1e-16f);
  float a0 = 0.f, a1 = 0.f, a2 = 0.f, a3 = 0.f;
  if (deg <= MAXDEG) {
    int j = 0;
    for (; j + 4 <= deg; j += 4) {
      float4 e0 = alL[w][j], e1 = alL[w][j + 1], e2 = alL[w][j + 2], e3 = alL[w][j + 3];
      int q0 = slL[w][j], q1 = slL[w][j + 1], q2 = slL[w][j + 2], q3 = slL[w][j + 3];
      float v0 = __bfloat162float(xh[(size_t)q0 * 64 + lane]);
      float v1 = __bfloat162float(xh[(size_t)q1 * 64 + lane]);
      float v2 = __bfloat162float(xh[(size_t)q2 * 64 + lane]);
      float v3 = __bfloat162float(xh[(size_t)q3 * 64 + lane]);
      a0 = fmaf(e0.x, v0, a0); a1 = fmaf(e0.y, v0, a1);
      a2 = fmaf(e0.z, v0, a2); a3 = fmaf(e0.w, v0, a3);
      a0 = fmaf(e1.x, v1, a0); a1 = fmaf(e1.y, v1, a1);
      a2 = fmaf(e1.z, v1, a2); a3 = fmaf(e1.w, v1, a3);
      a0 = fmaf(e2.x, v2, a0); a1 = fmaf(e2.y, v2, a1);
      a2 = fmaf(e2.z, v2, a2); a3 = fmaf(e2.w, v2, a3);
      a0 = fmaf(e3.x, v3, a0); a1 = fmaf(e3.y, v3, a1);
      a2 = fmaf(e3.z, v3, a2); a3 = fmaf(e3.w, v3, a3);
    }
    for (; j < deg; ++j) {
      float4 e0 = alL[w][j];
      int q0 = slL[w][j];
      float v0 = __bfloat162float(xh[(size_t)q0 * 64 + lane]);
      a0 = fmaf(e0.x, v0, a0); a1 = fmaf(e0.y, v0, a1);
      a2 = fmaf(e0.z, v0, a2); a3 = fmaf(e0.w, v0, a3);
    }
  } else {
    for (int b = start; b < end; b += 64) {
      int cnt = end - b;
      if (cnt > 64) cnt = 64;
      int idx = b + lane;
      int sl = 0;
      float e0 = 0.f, e1 = 0.f, e2 = 0.f, e3 = 0.f;
      if (idx < end) {
        sl = srt[idx];
        float4 as = asrc4[sl];
        e0 = __expf(lrelu(as.x + ad.x));
        e1 = __expf(lrelu(as.y + ad.y));
        e2 = __expf(lrelu(as.z + ad.z));
        e3 = __expf(lrelu(as.w + ad.w));
      }
      for (int j = 0; j < cnt; ++j) {
        int sj = __shfl(sl, j, 64);
        float b0 = __shfl(e0, j, 64), b1 = __shfl(e1, j, 64);
        float b2 = __shfl(e2, j, 64), b3 = __shfl(e3, j, 64);
        float v = __bfloat162float(xh[(size_t)sj * 64 + lane]);
        a0 = fmaf(b0, v, a0); a1 = fmaf(b1, v, a1);
        a2 = fmaf(b2, v, a2); a3 = fmaf(b3, v, a3);
      }
    }
  }
  __hip_bfloat16* ao = agg + (size_t)n * 256;
  ao[lane] = __float2bfloat16(a0 * r0);
  ao[64 + lane] = __float2bfloat16(a1 * r1);
  ao[128 + lane] = __float2bfloat16(a2 * r2);
  ao[192 + lane] = __float2bfloat16(a3 * r3);
}

// ---- Projection: bf16 agg -> f32 LDS [proven r13]
__global__ __launch_bounds__(256) void proj_kernel(
    const __hip_bfloat16* __restrict__ agg, const float* __restrict__ W,
    const float* __restrict__ bias, float* __restrict__ out, int N) {
  __shared__ float aggL[4][256];   // 4KB
  __shared__ float pL[4][4][64];   // 4KB
  int t = threadIdx.x, w = t >> 6, lane = t & 63;
  float Wreg[64];  // W[k, w*64 + lane]
#pragma unroll
  for (int k = 0; k < 64; ++k) Wreg[k] = W[(size_t)k * 256 + w * 64 + lane];
  float bv = bias[lane];
  int ngroups = (N + 3) >> 2;
  for (int g = blockIdx.x; g < ngroups; g += gridDim.x) {
    int n0 = g * 4;
    __syncthreads();
    {
      int nn = n0 + w;
      if (nn < N) {
        ushort4 u = ((const ushort4*)(agg + (size_t)nn * 256))[t & 63];
        float4 f;
        f.x = __bfloat162float(*(__hip_bfloat16*)&u.x);
        f.y = __bfloat162float(*(__hip_bfloat16*)&u.y);
        f.z = __bfloat162float(*(__hip_bfloat16*)&u.z);
        f.w = __bfloat162float(*(__hip_bfloat16*)&u.w);
        *(float4*)&aggL[w][(t & 63) * 4] = f;
      } else {
        *(float4*)&aggL[w][(t & 63) * 4] = make_float4(0.f, 0.f, 0.f, 0.f);
      }
    }
    __syncthreads();
    float acc0 = 0.f, acc1 = 0.f, acc2 = 0.f, acc3 = 0.f;
#pragma unroll
    for (int k4 = 0; k4 < 16; ++k4) {
      float4 av0 = *(const float4*)&aggL[0][w * 64 + k4 * 4];
      float4 av1 = *(const float4*)&aggL[1][w * 64 + k4 * 4];
      float4 av2 = *(const float4*)&aggL[2][w * 64 + k4 * 4];
      float4 av3 = *(const float4*)&aggL[3][w * 64 + k4 * 4];
      float w0 = Wreg[k4 * 4 + 0], w1 = Wreg[k4 * 4 + 1];
      float w2 = Wreg[k4 * 4 + 2], w3 = Wreg[k4 * 4 + 3];
      acc0 = fmaf(av0.x, w0, acc0); acc0 = fmaf(av0.y, w1, acc0);
      acc0 = fmaf(av0.z, w2, acc0); acc0 = fmaf(av0.w, w3, acc0);
      acc1 = fmaf(av1.x, w0, acc1); acc1 = fmaf(av1.y, w1, acc1);
      acc1 = fmaf(av1.z, w2, acc1); acc1 = fmaf(av1.w, w3, acc1);
      acc2 = fmaf(av2.x, w0, acc2); acc2 = fmaf(av2.y, w1, acc2);
      acc2 = fmaf(av2.z, w2, acc2); acc2 = fmaf(av2.w, w3, acc2);
      acc3 = fmaf(av3.x, w0, acc3); acc3 = fmaf(av3.y, w1, acc3);
      acc3 = fmaf(av3.z, w2, acc3); acc3 = fmaf(av3.w, w3, acc3);
    }
    pL[w][0][lane] = acc0;
    pL[w][1][lane] = acc1;
    pL[w][2][lane] = acc2;
    pL[w][3][lane] = acc3;
    __syncthreads();
    int nn = n0 + w;
    if (nn < N) {
      out[(size_t)nn * 64 + lane] = pL[0][w][lane] + pL[1][w][lane] +
                                    pL[2][w][lane] + pL[3][w][lane] + bv;
    }
  }
}

extern "C" void kernel_launch(void* const* d_in, const int* in_sizes, int n_in,
                              void* d_out, int out_size, void* d_ws, size_t ws_size,
                              hipStream_t stream) {
  const float* meta_x = (const float*)d_in[0];
  const int* ei = (const int*)d_in[1];  // int32 edge index [2,E] flat
  const float* W = (const float*)d_in[2];
  const float* att_src = (const float*)d_in[3];
  const float* att_dst = (const float*)d_in[4];
  const float* bias = (const float*)d_in[5];
  float* out = (float*)d_out;

  int N = in_sizes[0] / 64;
  int E = in_sizes[1] / 2;
  int ET = E + N;
  int ntiles = (N + 255) / 256;

  char* ws = (char*)d_ws;
  size_t off = 0;
  auto alloc = [&](size_t bytes) {
    size_t o = off;
    off += (bytes + 255) & ~(size_t)255;
    return o;
  };
  size_t o_wsrc = alloc(64 * 4 * sizeof(float));
  size_t o_wdst = alloc(64 * 4 * sizeof(float));
  size_t o_asrc = alloc((size_t)N * 4 * sizeof(float));
  size_t o_adst = alloc((size_t)N * 4 * sizeof(float));
  size_t o_cnt = alloc((size_t)ntiles * 256 * sizeof(int));  // zero-padded to tiles
  size_t o_row = alloc(((size_t)N + 1) * sizeof(int));
  size_t o_cur = alloc((size_t)N * sizeof(int));
  size_t o_srt = alloc((size_t)ET * sizeof(int));
  size_t o_ts = alloc((size_t)ntiles * sizeof(int));
  size_t o_xh = alloc((size_t)N * 64 * sizeof(__hip_bfloat16));   // 6.4 MB
  size_t o_agg = alloc((size_t)N * 256 * sizeof(__hip_bfloat16)); // 25.6 MB
  bool split = (ws_size >= off);
  (void)split;

  float* wsrc = (float*)(ws + o_wsrc);
  float* wdst = (float*)(ws + o_wdst);
  float4* asrc4 = (float4*)(ws + o_asrc);
  float4* adst4 = (float4*)(ws + o_adst);
  int* cnt = (int*)(ws + o_cnt);
  int* row = (int*)(ws + o_row);
  int* cur = (int*)(ws + o_cur);
  int* srt = (int*)(ws + o_srt);
  int* tsum = (int*)(ws + o_ts);
  __hip_bfloat16* xh = (__hip_bfloat16*)(ws + o_xh);
  __hip_bfloat16* aggp = (__hip_bfloat16*)(ws + o_agg);

  int n4 = ntiles * 64;  // int4 count covering the padded cnt region
  prep_kernel<<<64, 256, 0, stream>>>((int4*)cnt, n4, W, att_src, att_dst, wsrc, wdst);

  if ((E & 3) == 0) {
    int nbh = ((E >> 2) + N + 255) / 256;
    int nbn = (N + 3) / 4;
    nh_kernel<<<nbh + nbn, 256, 0, stream>>>(meta_x, (const float4*)wsrc,
                                             (const float4*)wdst, asrc4, adst4, xh,
                                             ei, cnt, E, N, nbh);
  } else {
    nattn_kernel<<<(N + 3) / 4, 256, 0, stream>>>(meta_x, (const float4*)wsrc,
                                                  (const float4*)wdst, asrc4, adst4, xh, N);
    hist_kernel<<<(ET + 255) / 256, 256, 0, stream>>>(ei, cnt, E, N);
  }

  if (ntiles <= 256) {
    scanABC_kernel<<<ntiles, 256, 0, stream>>>(cnt, row, cur, N, ntiles);
  } else {
    scanA_kernel<<<ntiles, 256, 0, stream>>>(cnt, tsum, N);
    scanB_kernel<<<1, 256, 0, stream>>>(tsum, ntiles);
    scanC_kernel<<<ntiles, 256, 0, stream>>>(cnt, tsum, row, cur, N);
  }

  if ((E & 3) == 0) {
    scatter8_kernel<<<2048, 256, 0, stream>>>(ei, cur, srt, E, N);
  } else {
    scatter_kernel<<<(ET + 255) / 256, 256, 0, stream>>>(ei, cur, srt, E, N);
  }

  agg_kernel<<<(N + 3) / 4, 256, 0, stream>>>(srt, row, asrc4, adst4, xh, aggp, N);
  int ngroups = (N + 3) / 4;
  int pgrid = ngroups < 1024 ? ngroups : 1024;
  proj_kernel<<<pgrid, 256, 0, stream>>>(aggp, W, bias, out, N);
}